// Round 9
// baseline (232.582 us; speedup 1.0000x reference)
//
#include <hip/hip_runtime.h>
#include <hip/hip_bf16.h>
#include <stdint.h>

#define MROWS 16384   // B*S
#define KDIM  2048
#define NDIM  2048
#define LEAFD 13
#define RANKD 4

typedef __bf16 bf16x8 __attribute__((ext_vector_type(8)));
typedef float  f32x4  __attribute__((ext_vector_type(4)));

// ---------------------------------------------------------------------------
// Kernel 1: w_bf[o,i] = bf16( weight[o,i] + sum_r L0[r,o2,i2]*L1[r,o1,i1]*L2[r,o0,i0] )
// ---------------------------------------------------------------------------
__global__ void build_w_kernel(const float* __restrict__ weight,
                               const float* __restrict__ leaf,
                               __hip_bfloat16* __restrict__ wbf) {
    __shared__ float ll[3 * RANKD * LEAFD * LEAFD];
    for (int t = threadIdx.x; t < 3 * RANKD * LEAFD * LEAFD; t += blockDim.x)
        ll[t] = leaf[t];
    __syncthreads();
    int idx = blockIdx.x * blockDim.x + threadIdx.x;
    if (idx >= NDIM * KDIM) return;
    int o = idx / KDIM, i = idx % KDIM;
    int o2 = o / 169, o1 = (o / 13) % 13, o0 = o % 13;
    int i2 = i / 169, i1 = (i / 13) % 13, i0 = i % 13;
    float d = 0.f;
#pragma unroll
    for (int r = 0; r < RANKD; ++r) {
        float a = ll[( r            * LEAFD + o2) * LEAFD + i2];
        float b = ll[((RANKD   + r) * LEAFD + o1) * LEAFD + i1];
        float c = ll[((2*RANKD + r) * LEAFD + o0) * LEAFD + i0];
        d += a * b * c;
    }
    wbf[idx] = __float2bfloat16(weight[idx] + d);
}

// ---------------------------------------------------------------------------
// Kernel 2: fused GEMM. C[m,n] = sum_k A32[m,k]*W[n,k] + bias[n].
// R2 structure (256x256, BK=64, 16x16x32 MFMA, 8 waves 2Mx4N, 2-buf x 4-slot
// LDS 128KB, zero-conflict involution swizzle, vmcnt-counted B staging) with
// A-staging REPLACED: fp32 global -> regs (issued 2 phases early) -> cvt bf16
// -> swizzled ds_write. Deletes the separate cvt pass entirely.
//
// Slots per 64KB buf: {0: A-klo, 1: B-klo, 2: A-khi, 3: B-khi}, 16KB each
// (256 rows x 32 k bf16). Storage map: 16B-chunk linear index p stored at
// swz(p) = p ^ ((p>>3)&7) (involution). Reads use the same map (R2: measured
// 0 conflicts). A lane writes chunks {p16, p16+1} (p16 even); their storage
// positions are {swz(p16), swz(p16)^1} — the SAME 32B-aligned pair — so the
// second 16B write goes to byte offset aWoff ^ 16 (NOT aWoff + 16; that was
// the R8 NaN bug: when bit0 of the XOR mask is 1, +16 hits a foreign chunk
// and leaves swz(p16)^1 unwritten).
//
// Per tile t (buf c = t&1), phases p0..p3:
//  p0: ds_read klo frags(mh0) | write A-khi(t+1)->c^1 | issue A-klo fp32(t+2)
//  p1: ds_read klo frags(mh1) | gload B-khi(t+1)->c^1 | vmcnt(8)
//  p2: ds_read khi frags(mh0) | write A-klo(t+2)->c   | issue A-khi fp32(t+2)
//  p3: ds_read khi frags(mh1) | gload B-klo(t+2)->c   | vmcnt(8)
// Each phase: barrier, lgkm0, setprio, 16 MFMA, setprio, barrier.
// ---------------------------------------------------------------------------

__device__ __forceinline__ void gload16(const __hip_bfloat16* g, char* l) {
    __builtin_amdgcn_global_load_lds((const __attribute__((address_space(1))) void*)g,
                                     (__attribute__((address_space(3))) void*)l,
                                     16, 0, 0);
}

#define BSTAGE(kb, bufi, slot) do {                                               \
    gload16(Bbase + (kb) + gOffB0, smemc + (bufi)*65536 + (slot)*16384 + lOff0);  \
    gload16(Bbase + (kb) + gOffB1, smemc + (bufi)*65536 + (slot)*16384 + lOff1);  \
} while (0)

// Issue 4 float4 loads (64B contiguous per lane; wave = 32 rows x 128B).
#define A_ISSUE(S, koff) do {                                                     \
    S##0 = *(const f32x4*)(Aptr + (koff) + 0);                                    \
    S##1 = *(const f32x4*)(Aptr + (koff) + 4);                                    \
    S##2 = *(const f32x4*)(Aptr + (koff) + 8);                                    \
    S##3 = *(const f32x4*)(Aptr + (koff) + 12);                                   \
} while (0)

// Convert 16 fp32 -> bf16, write 2 x 16B at the swizzled pair {aWoff, aWoff^16}.
#define A_WRITE(S, bufi, slot) do {                                               \
    __hip_bfloat16 wtmp[16];                                                      \
    wtmp[ 0] = __float2bfloat16(S##0[0]); wtmp[ 1] = __float2bfloat16(S##0[1]);   \
    wtmp[ 2] = __float2bfloat16(S##0[2]); wtmp[ 3] = __float2bfloat16(S##0[3]);   \
    wtmp[ 4] = __float2bfloat16(S##1[0]); wtmp[ 5] = __float2bfloat16(S##1[1]);   \
    wtmp[ 6] = __float2bfloat16(S##1[2]); wtmp[ 7] = __float2bfloat16(S##1[3]);   \
    wtmp[ 8] = __float2bfloat16(S##2[0]); wtmp[ 9] = __float2bfloat16(S##2[1]);   \
    wtmp[10] = __float2bfloat16(S##2[2]); wtmp[11] = __float2bfloat16(S##2[3]);   \
    wtmp[12] = __float2bfloat16(S##3[0]); wtmp[13] = __float2bfloat16(S##3[1]);   \
    wtmp[14] = __float2bfloat16(S##3[2]); wtmp[15] = __float2bfloat16(S##3[3]);   \
    *(bf16x8*)(smemc + (bufi)*65536 + (slot)*16384 + aWoff)        = *(bf16x8*)(wtmp);     \
    *(bf16x8*)(smemc + (bufi)*65536 + (slot)*16384 + (aWoff ^ 16)) = *(bf16x8*)(wtmp + 8); \
} while (0)

#define LOAD_A(mh, kk, bufc)                                                        \
    af0 = *(const bf16x8*)(smemc + (bufc)*65536 + (kk)*32768 + offA[(mh)*4+0]);     \
    af1 = *(const bf16x8*)(smemc + (bufc)*65536 + (kk)*32768 + offA[(mh)*4+1]);     \
    af2 = *(const bf16x8*)(smemc + (bufc)*65536 + (kk)*32768 + offA[(mh)*4+2]);     \
    af3 = *(const bf16x8*)(smemc + (bufc)*65536 + (kk)*32768 + offA[(mh)*4+3]);

#define LOAD_B(kk, bufc)                                                                    \
    bf0 = *(const bf16x8*)(smemc + (bufc)*65536 + (kk)*32768 + 16384 + offB[0]);            \
    bf1 = *(const bf16x8*)(smemc + (bufc)*65536 + (kk)*32768 + 16384 + offB[1]);            \
    bf2 = *(const bf16x8*)(smemc + (bufc)*65536 + (kk)*32768 + 16384 + offB[2]);            \
    bf3 = *(const bf16x8*)(smemc + (bufc)*65536 + (kk)*32768 + 16384 + offB[3]);

#define MFMA_Q(mh) do {                                                                   \
    acc[(mh)*4+0][0] = __builtin_amdgcn_mfma_f32_16x16x32_bf16(af0, bf0, acc[(mh)*4+0][0], 0,0,0); \
    acc[(mh)*4+1][0] = __builtin_amdgcn_mfma_f32_16x16x32_bf16(af1, bf0, acc[(mh)*4+1][0], 0,0,0); \
    acc[(mh)*4+2][0] = __builtin_amdgcn_mfma_f32_16x16x32_bf16(af2, bf0, acc[(mh)*4+2][0], 0,0,0); \
    acc[(mh)*4+3][0] = __builtin_amdgcn_mfma_f32_16x16x32_bf16(af3, bf0, acc[(mh)*4+3][0], 0,0,0); \
    acc[(mh)*4+0][1] = __builtin_amdgcn_mfma_f32_16x16x32_bf16(af0, bf1, acc[(mh)*4+0][1], 0,0,0); \
    acc[(mh)*4+1][1] = __builtin_amdgcn_mfma_f32_16x16x32_bf16(af1, bf1, acc[(mh)*4+1][1], 0,0,0); \
    acc[(mh)*4+2][1] = __builtin_amdgcn_mfma_f32_16x16x32_bf16(af2, bf1, acc[(mh)*4+2][1], 0,0,0); \
    acc[(mh)*4+3][1] = __builtin_amdgcn_mfma_f32_16x16x32_bf16(af3, bf1, acc[(mh)*4+3][1], 0,0,0); \
    acc[(mh)*4+0][2] = __builtin_amdgcn_mfma_f32_16x16x32_bf16(af0, bf2, acc[(mh)*4+0][2], 0,0,0); \
    acc[(mh)*4+1][2] = __builtin_amdgcn_mfma_f32_16x16x32_bf16(af1, bf2, acc[(mh)*4+1][2], 0,0,0); \
    acc[(mh)*4+2][2] = __builtin_amdgcn_mfma_f32_16x16x32_bf16(af2, bf2, acc[(mh)*4+2][2], 0,0,0); \
    acc[(mh)*4+3][2] = __builtin_amdgcn_mfma_f32_16x16x32_bf16(af3, bf2, acc[(mh)*4+3][2], 0,0,0); \
    acc[(mh)*4+0][3] = __builtin_amdgcn_mfma_f32_16x16x32_bf16(af0, bf3, acc[(mh)*4+0][3], 0,0,0); \
    acc[(mh)*4+1][3] = __builtin_amdgcn_mfma_f32_16x16x32_bf16(af1, bf3, acc[(mh)*4+1][3], 0,0,0); \
    acc[(mh)*4+2][3] = __builtin_amdgcn_mfma_f32_16x16x32_bf16(af2, bf3, acc[(mh)*4+2][3], 0,0,0); \
    acc[(mh)*4+3][3] = __builtin_amdgcn_mfma_f32_16x16x32_bf16(af3, bf3, acc[(mh)*4+3][3], 0,0,0); \
} while (0)

#define BARRIER_IN do {                                     \
    __builtin_amdgcn_sched_barrier(0);                      \
    __builtin_amdgcn_s_barrier();                           \
    asm volatile("s_waitcnt lgkmcnt(0)" ::: "memory");      \
    __builtin_amdgcn_sched_barrier(0);                      \
    __builtin_amdgcn_s_setprio(1);                          \
} while (0)

#define BARRIER_OUT do {                                    \
    __builtin_amdgcn_s_setprio(0);                          \
    __builtin_amdgcn_sched_barrier(0);                      \
    __builtin_amdgcn_s_barrier();                           \
    __builtin_amdgcn_sched_barrier(0);                      \
} while (0)

#define WAIT8 asm volatile("s_waitcnt vmcnt(8)" ::: "memory")
#define WAIT4 asm volatile("s_waitcnt vmcnt(4)" ::: "memory")
#define WAIT2 asm volatile("s_waitcnt vmcnt(2)" ::: "memory")
#define WAIT0 asm volatile("s_waitcnt vmcnt(0)" ::: "memory")
#define WNONE do {} while (0)

#define KTILE5(t, bufc, WKHI_, SAKLO_, SBH_, WKLO_, SAKHI_, SBL_, W1_, W3_) do { \
    /* p0 */                                                                     \
    LOAD_B(0, bufc); LOAD_A(0, 0, bufc);                                         \
    if (WKHI_)  { A_WRITE(kh, (bufc)^1, 2); }                                    \
    if (SAKLO_) { A_ISSUE(kl, ((t)+2)*64); }                                     \
    BARRIER_IN; MFMA_Q(0); BARRIER_OUT;                                          \
    /* p1 */                                                                     \
    LOAD_A(1, 0, bufc);                                                          \
    if (SBH_) BSTAGE(((t)+1)*64+32, (bufc)^1, 3);                                \
    W1_;                                                                         \
    BARRIER_IN; MFMA_Q(1); BARRIER_OUT;                                          \
    /* p2 */                                                                     \
    LOAD_B(1, bufc); LOAD_A(0, 1, bufc);                                         \
    if (WKLO_)  { A_WRITE(kl, (bufc), 0); }                                      \
    if (SAKHI_) { A_ISSUE(kh, ((t)+2)*64+32); }                                  \
    BARRIER_IN; MFMA_Q(0); BARRIER_OUT;                                          \
    /* p3 */                                                                     \
    LOAD_A(1, 1, bufc);                                                          \
    if (SBL_) BSTAGE(((t)+2)*64, (bufc), 1);                                     \
    W3_;                                                                         \
    BARRIER_IN; MFMA_Q(1); BARRIER_OUT;                                          \
} while (0)

__global__ __launch_bounds__(512, 2) void gemm5_kernel(const float* __restrict__ A32,
                                                       const __hip_bfloat16* __restrict__ Wb,
                                                       const float* __restrict__ bias,
                                                       float* __restrict__ C) {
    __shared__ __align__(16) __hip_bfloat16 smem[2][4][8192];  // 128 KiB
    char* smemc = (char*)smem;

    const int tid  = threadIdx.x;
    const int lane = tid & 63;
    const int wid  = tid >> 6;        // 0..7
    const int wr   = wid >> 2;        // 0..1  (M half)
    const int wc   = wid & 3;         // 0..3  (N quarter)

    // T1: XCD-aware swizzle (nwg=512, 512%8==0 -> bijective).
    const int bid = blockIdx.x;
    const int swz = (bid & 7) * 64 + (bid >> 3);
    const int bn  = swz >> 6;         // 0..7
    const int bm  = swz & 63;         // 0..63

    const __hip_bfloat16* Bbase = Wb + (size_t)bn * 256 * KDIM;

    // --- A reg-staging addressing ---
    // lane pair covers one row's 128B fp32: row = wid*32 + (lane>>1),
    // k-offset base (lane&1)*16.
    const int arow = wid * 32 + (lane >> 1);
    const float* Aptr = A32 + ((size_t)bm * 256 + arow) * KDIM + (lane & 1) * 16;
    // ds_write chunks p16 (even) and p16+1 -> storage pair {swz(p16), swz(p16)^1}.
    const int p16   = arow * 4 + (lane & 1) * 2;
    const int aWoff = (p16 ^ ((p16 >> 3) & 7)) * 16;

    // --- B staging source offsets (inverse-swizzled global, linear LDS dest) ---
    const int c0  = wid * 64 + lane;          // chunk 0..511
    const int c1  = 512 + c0;                 // chunk 512..1023
    const int cs0 = c0 ^ ((c0 >> 3) & 7);
    const int cs1 = c1 ^ ((c1 >> 3) & 7);
    const int gOffB0 = (cs0 >> 2) * KDIM + (cs0 & 3) * 8;   // elements
    const int gOffB1 = (cs1 >> 2) * KDIM + (cs1 & 3) * 8;
    const int lOff0 = wid * 1024;                           // bytes (wave-uniform)
    const int lOff1 = 8192 + wid * 1024;

    // --- swizzled ds_read byte offsets within a 16 KB slot (R2 map, 0-conflict) ---
    const int rsel = lane & 15;
    const int kby  = (lane >> 4) * 16;
    int offA[8], offB[4];
#pragma unroll
    for (int m = 0; m < 8; ++m) {
        int a = (wr * 128 + m * 16 + rsel) * 64 + kby;
        offA[m] = a ^ (((a >> 7) & 7) << 4);
    }
#pragma unroll
    for (int n = 0; n < 4; ++n) {
        int a = (wc * 64 + n * 16 + rsel) * 64 + kby;
        offB[n] = a ^ (((a >> 7) & 7) << 4);
    }

    f32x4 acc[8][4];
#pragma unroll
    for (int m = 0; m < 8; ++m)
#pragma unroll
        for (int n = 0; n < 4; ++n)
            acc[m][n] = (f32x4){0.f, 0.f, 0.f, 0.f};

    bf16x8 af0, af1, af2, af3, bf0, bf1, bf2, bf3;
    f32x4 kl0, kl1, kl2, kl3;   // A-klo fp32 in-flight set
    f32x4 kh0, kh1, kh2, kh3;   // A-khi fp32 in-flight set

    // --- prologue ---
    // A: direct-stage tiles 0,1 (klo+khi each); auto-waits serialize (one-time).
    A_ISSUE(kl,  0); A_WRITE(kl, 0, 0);
    A_ISSUE(kl, 32); A_WRITE(kl, 0, 2);
    A_ISSUE(kl, 64); A_WRITE(kl, 1, 0);
    A_ISSUE(kl, 96); A_WRITE(kl, 1, 2);
    // B: tile0 klo,khi + tile1 klo (6 gloads).
    BSTAGE( 0, 0, 1);
    BSTAGE(32, 0, 3);
    BSTAGE(64, 1, 1);
    WAIT4;                                              // t0 B fully landed
    asm volatile("s_waitcnt lgkmcnt(0)" ::: "memory");  // publish A writes
    __builtin_amdgcn_sched_barrier(0);
    __builtin_amdgcn_s_barrier();
    __builtin_amdgcn_sched_barrier(0);

    // --- main loop: KDIM/64 = 32 K-tiles ---
    KTILE5(0, 0, 0, 1, 1, 1, 1, 1, WAIT8, WAIT8);       // WKHI off (prologue did khi(1))
    for (int t = 1; t < 29; t += 2) {
        KTILE5(t,     1, 1, 1, 1, 1, 1, 1, WAIT8, WAIT8);
        KTILE5(t + 1, 0, 1, 1, 1, 1, 1, 1, WAIT8, WAIT8);
    }
    KTILE5(29, 1, 1, 1, 1, 1, 1, 1, WAIT8, WAIT8);      // stages tile 31
    KTILE5(30, 0, 1, 0, 1, 0, 0, 0, WAIT4, WAIT2);      // writes khi(31); gloads Bkhi(31)
    KTILE5(31, 1, 0, 0, 0, 0, 0, 0, WAIT0, WNONE);

    // --- epilogue: C/D layout col = lane&15, row = (lane>>4)*4 + r ---
    const int col0 = lane & 15;
    const int r0   = (lane >> 4) * 4;
#pragma unroll
    for (int n = 0; n < 4; ++n) {
        const int cg = bn * 256 + wc * 64 + n * 16 + col0;
        const float bv = bias[cg];
#pragma unroll
        for (int m = 0; m < 8; ++m) {
            const size_t rg = (size_t)bm * 256 + wr * 128 + m * 16 + r0;
#pragma unroll
            for (int r = 0; r < 4; ++r)
                C[(rg + r) * NDIM + cg] = acc[m][n][r] + bv;
        }
    }
}

// ---------------------------------------------------------------------------
// Fallback: naive fused fp32 GEMM (only if workspace too small).
// ---------------------------------------------------------------------------
__global__ void naive_kernel(const float* __restrict__ x,
                             const float* __restrict__ leaf,
                             const float* __restrict__ W,
                             const float* __restrict__ bias,
                             float* __restrict__ out) {
    long idx = (long)blockIdx.x * blockDim.x + threadIdx.x;
    if (idx >= (long)MROWS * NDIM) return;
    int  o = (int)(idx % NDIM);
    long m = idx / NDIM;
    int o2 = o / 169, o1 = (o / 13) % 13, o0 = o % 13;
    float acc = 0.f;
    for (int i = 0; i < KDIM; ++i) {
        int i2 = i / 169, i1 = (i / 13) % 13, i0 = i % 13;
        float d = 0.f;
#pragma unroll
        for (int r = 0; r < RANKD; ++r)
            d += leaf[( r     * LEAFD + o2) * LEAFD + i2]
               * leaf[((4 + r) * LEAFD + o1) * LEAFD + i1]
               * leaf[((8 + r) * LEAFD + o0) * LEAFD + i0];
        acc += x[m * KDIM + i] * (W[(long)o * KDIM + i] + d);
    }
    out[idx] = acc + bias[o];
}

// ---------------------------------------------------------------------------
extern "C" void kernel_launch(void* const* d_in, const int* in_sizes, int n_in,
                              void* d_out, int out_size, void* d_ws, size_t ws_size,
                              hipStream_t stream) {
    const float* x      = (const float*)d_in[0];
    const float* leaf   = (const float*)d_in[1];
    const float* weight = (const float*)d_in[2];
    const float* bias   = (const float*)d_in[3];
    float* out = (float*)d_out;

    const size_t needW = (size_t)NDIM * KDIM * sizeof(__hip_bfloat16);  // 8 MiB

    if (ws_size >= needW) {
        __hip_bfloat16* wb = (__hip_bfloat16*)d_ws;
        build_w_kernel<<<(NDIM * KDIM + 255) / 256, 256, 0, stream>>>(weight, leaf, wb);
        gemm5_kernel<<<(MROWS / 256) * (NDIM / 256), 512, 0, stream>>>(x, wb, bias, out);
    } else {
        long total = (long)MROWS * NDIM;
        naive_kernel<<<(int)((total + 255) / 256), 256, 0, stream>>>(x, leaf, weight, bias, out);
    }
}

// Round 10
// 212.431 us; speedup vs baseline: 1.0949x; 1.0949x over previous
//
#include <hip/hip_runtime.h>
#include <hip/hip_bf16.h>
#include <stdint.h>

#define MROWS 16384   // B*S
#define KDIM  2048
#define NDIM  2048
#define LEAFD 13
#define RANKD 4

typedef __bf16 bf16x8 __attribute__((ext_vector_type(8)));
typedef float  f32x4  __attribute__((ext_vector_type(4)));

// ---------------------------------------------------------------------------
// Kernel 1: w_bf[o,i] = bf16( weight[o,i] + sum_r L0[r,o2,i2]*L1[r,o1,i1]*L2[r,o0,i0] )
// ---------------------------------------------------------------------------
__global__ void build_w_kernel(const float* __restrict__ weight,
                               const float* __restrict__ leaf,
                               __hip_bfloat16* __restrict__ wbf) {
    __shared__ float ll[3 * RANKD * LEAFD * LEAFD];
    for (int t = threadIdx.x; t < 3 * RANKD * LEAFD * LEAFD; t += blockDim.x)
        ll[t] = leaf[t];
    __syncthreads();
    int idx = blockIdx.x * blockDim.x + threadIdx.x;
    if (idx >= NDIM * KDIM) return;
    int o = idx / KDIM, i = idx % KDIM;
    int o2 = o / 169, o1 = (o / 13) % 13, o0 = o % 13;
    int i2 = i / 169, i1 = (i / 13) % 13, i0 = i % 13;
    float d = 0.f;
#pragma unroll
    for (int r = 0; r < RANKD; ++r) {
        float a = ll[( r            * LEAFD + o2) * LEAFD + i2];
        float b = ll[((RANKD   + r) * LEAFD + o1) * LEAFD + i1];
        float c = ll[((2*RANKD + r) * LEAFD + o0) * LEAFD + i0];
        d += a * b * c;
    }
    wbf[idx] = __float2bfloat16(weight[idx] + d);
}

// ---------------------------------------------------------------------------
// Kernel 2: fused GEMM, A read as fp32 and converted AFTER ds_read.
// C[m,n] = sum_k A32[m,k]*W[n,k] + bias[n]. 256x256 tile, BK=32, 16x16x32
// MFMA, 8 waves (2M x 4N), per-wave 128x64. No separate cvt pass.
//
// LDS: 3 bufs x {A-fp32 32KB, B-bf16 16KB} = 144 KB. Stage t+2 during t via
// global_load_lds ONLY (async; R9 lesson: reg-routed staging serializes).
// One vmcnt(6) per K-tile at p1 (covers loads issued 2 tiles earlier).
//
// A slot: 256 rows x 128B (8 x 16B chunks). Storage: chunk col c of row r at
// c ^ (r&7). Frag read (row=wr*128+m*16+(lane&15), chunks kq*2, kq*2+1 where
// kq=lane>>4): per 16-lane quarter-wave every bank hit exactly 2x = b128
// floor (free, m136). Staging inverse-map keeps 8 lanes covering each full
// 128B row (coalesced).
// B slot: identical to R2 (measured 0 conflicts).
//
// Per K-tile t (bufc=t%3, bufs=(t+2)%3), 2 phases:
//  p0: ds_read B(4) + A m0-3 (8 fp32 b128) | stage Aj0,Aj1,Bj0 -> bufs
//      barrier, lgkm0, setprio: cvt m0-3 (16 VALU), 16 MFMA; barrier
//  p1: ds_read A m4-7 (8) | stage Aj2,Aj3,Bj1 | vmcnt(6)
//      barrier, lgkm0, setprio: cvt m4-7, 16 MFMA; barrier
// ---------------------------------------------------------------------------

__device__ __forceinline__ void gload16(const void* g, char* l) {
    __builtin_amdgcn_global_load_lds((const __attribute__((address_space(1))) void*)g,
                                     (__attribute__((address_space(3))) void*)l,
                                     16, 0, 0);
}

__device__ __forceinline__ bf16x8 cvt8(f32x4 lo, f32x4 hi) {
    __hip_bfloat16 h[8];
    h[0] = __float2bfloat16(lo[0]); h[1] = __float2bfloat16(lo[1]);
    h[2] = __float2bfloat16(lo[2]); h[3] = __float2bfloat16(lo[3]);
    h[4] = __float2bfloat16(hi[0]); h[5] = __float2bfloat16(hi[1]);
    h[6] = __float2bfloat16(hi[2]); h[7] = __float2bfloat16(hi[3]);
    return *(bf16x8*)h;
}

#define BUFSZ 49152   // 32KB A + 16KB B

#define AST(t2, BS, j) \
    gload16(Abase32 + (size_t)(t2)*32 + gAoff[j], smemc + (BS)*BUFSZ + lOffA[j])
#define BST0(t2, BS) \
    gload16(Bbase + (t2)*32 + gOffB0, smemc + (BS)*BUFSZ + 32768 + lOffB0)
#define BST1(t2, BS) \
    gload16(Bbase + (t2)*32 + gOffB1, smemc + (BS)*BUFSZ + 32768 + lOffB1)

#define LOAD_B(BC)                                                              \
    bf0 = *(const bf16x8*)(smemc + (BC)*BUFSZ + 32768 + offB[0]);               \
    bf1 = *(const bf16x8*)(smemc + (BC)*BUFSZ + 32768 + offB[1]);               \
    bf2 = *(const bf16x8*)(smemc + (BC)*BUFSZ + 32768 + offB[2]);               \
    bf3 = *(const bf16x8*)(smemc + (BC)*BUFSZ + 32768 + offB[3]);

#define LDA32(mh, BC)                                                           \
    u0 = *(const f32x4*)(smemc + (BC)*BUFSZ + offA32[(mh)*4+0][0]);             \
    u1 = *(const f32x4*)(smemc + (BC)*BUFSZ + offA32[(mh)*4+0][1]);             \
    u2 = *(const f32x4*)(smemc + (BC)*BUFSZ + offA32[(mh)*4+1][0]);             \
    u3 = *(const f32x4*)(smemc + (BC)*BUFSZ + offA32[(mh)*4+1][1]);             \
    u4 = *(const f32x4*)(smemc + (BC)*BUFSZ + offA32[(mh)*4+2][0]);             \
    u5 = *(const f32x4*)(smemc + (BC)*BUFSZ + offA32[(mh)*4+2][1]);             \
    u6 = *(const f32x4*)(smemc + (BC)*BUFSZ + offA32[(mh)*4+3][0]);             \
    u7 = *(const f32x4*)(smemc + (BC)*BUFSZ + offA32[(mh)*4+3][1]);

#define CVT4 do {                                                               \
    af0 = cvt8(u0, u1); af1 = cvt8(u2, u3);                                     \
    af2 = cvt8(u4, u5); af3 = cvt8(u6, u7);                                     \
} while (0)

#define MFMA_Q(mh) do {                                                                   \
    acc[(mh)*4+0][0] = __builtin_amdgcn_mfma_f32_16x16x32_bf16(af0, bf0, acc[(mh)*4+0][0], 0,0,0); \
    acc[(mh)*4+1][0] = __builtin_amdgcn_mfma_f32_16x16x32_bf16(af1, bf0, acc[(mh)*4+1][0], 0,0,0); \
    acc[(mh)*4+2][0] = __builtin_amdgcn_mfma_f32_16x16x32_bf16(af2, bf0, acc[(mh)*4+2][0], 0,0,0); \
    acc[(mh)*4+3][0] = __builtin_amdgcn_mfma_f32_16x16x32_bf16(af3, bf0, acc[(mh)*4+3][0], 0,0,0); \
    acc[(mh)*4+0][1] = __builtin_amdgcn_mfma_f32_16x16x32_bf16(af0, bf1, acc[(mh)*4+0][1], 0,0,0); \
    acc[(mh)*4+1][1] = __builtin_amdgcn_mfma_f32_16x16x32_bf16(af1, bf1, acc[(mh)*4+1][1], 0,0,0); \
    acc[(mh)*4+2][1] = __builtin_amdgcn_mfma_f32_16x16x32_bf16(af2, bf1, acc[(mh)*4+2][1], 0,0,0); \
    acc[(mh)*4+3][1] = __builtin_amdgcn_mfma_f32_16x16x32_bf16(af3, bf1, acc[(mh)*4+3][1], 0,0,0); \
    acc[(mh)*4+0][2] = __builtin_amdgcn_mfma_f32_16x16x32_bf16(af0, bf2, acc[(mh)*4+0][2], 0,0,0); \
    acc[(mh)*4+1][2] = __builtin_amdgcn_mfma_f32_16x16x32_bf16(af1, bf2, acc[(mh)*4+1][2], 0,0,0); \
    acc[(mh)*4+2][2] = __builtin_amdgcn_mfma_f32_16x16x32_bf16(af2, bf2, acc[(mh)*4+2][2], 0,0,0); \
    acc[(mh)*4+3][2] = __builtin_amdgcn_mfma_f32_16x16x32_bf16(af3, bf2, acc[(mh)*4+3][2], 0,0,0); \
    acc[(mh)*4+0][3] = __builtin_amdgcn_mfma_f32_16x16x32_bf16(af0, bf3, acc[(mh)*4+0][3], 0,0,0); \
    acc[(mh)*4+1][3] = __builtin_amdgcn_mfma_f32_16x16x32_bf16(af1, bf3, acc[(mh)*4+1][3], 0,0,0); \
    acc[(mh)*4+2][3] = __builtin_amdgcn_mfma_f32_16x16x32_bf16(af2, bf3, acc[(mh)*4+2][3], 0,0,0); \
    acc[(mh)*4+3][3] = __builtin_amdgcn_mfma_f32_16x16x32_bf16(af3, bf3, acc[(mh)*4+3][3], 0,0,0); \
} while (0)

#define BARRIER_IN do {                                     \
    __builtin_amdgcn_sched_barrier(0);                      \
    __builtin_amdgcn_s_barrier();                           \
    asm volatile("s_waitcnt lgkmcnt(0)" ::: "memory");      \
    __builtin_amdgcn_sched_barrier(0);                      \
    __builtin_amdgcn_s_setprio(1);                          \
} while (0)

#define BARRIER_OUT do {                                    \
    __builtin_amdgcn_s_setprio(0);                          \
    __builtin_amdgcn_sched_barrier(0);                      \
    __builtin_amdgcn_s_barrier();                           \
    __builtin_amdgcn_sched_barrier(0);                      \
} while (0)

#define WAIT6 asm volatile("s_waitcnt vmcnt(6)" ::: "memory")
#define WAIT0 asm volatile("s_waitcnt vmcnt(0)" ::: "memory")
#define WNONE do {} while (0)

// One K-tile: 2 phases; stage t+2 -> bufs (3 gloads per phase); wait at p1.
#define KT(t, BC, BS, SG, WT) do {                                  \
    /* p0 */                                                        \
    LOAD_B(BC);                                                     \
    LDA32(0, BC);                                                   \
    if (SG) { AST((t)+2, BS, 0); AST((t)+2, BS, 1); BST0((t)+2, BS); } \
    BARRIER_IN;                                                     \
    CVT4;                                                           \
    MFMA_Q(0);                                                      \
    BARRIER_OUT;                                                    \
    /* p1 */                                                        \
    LDA32(1, BC);                                                   \
    if (SG) { AST((t)+2, BS, 2); AST((t)+2, BS, 3); BST1((t)+2, BS); } \
    WT;                                                             \
    BARRIER_IN;                                                     \
    CVT4;                                                           \
    MFMA_Q(1);                                                      \
    BARRIER_OUT;                                                    \
} while (0)

__global__ __launch_bounds__(512, 2) void gemm6_kernel(const float* __restrict__ A32,
                                                       const __hip_bfloat16* __restrict__ Wb,
                                                       const float* __restrict__ bias,
                                                       float* __restrict__ C) {
    __shared__ __align__(16) char smem_raw[3 * BUFSZ];   // 144 KiB
    char* smemc = smem_raw;

    const int tid  = threadIdx.x;
    const int lane = tid & 63;
    const int wid  = tid >> 6;        // 0..7
    const int wr   = wid >> 2;        // 0..1  (M half)
    const int wc   = wid & 3;         // 0..3  (N quarter)

    // T1: XCD-aware swizzle (nwg=512, 512%8==0 -> bijective).
    const int bid = blockIdx.x;
    const int swz = (bid & 7) * 64 + (bid >> 3);
    const int bn  = swz >> 6;         // 0..7
    const int bm  = swz & 63;         // 0..63

    const float*          Abase32 = A32 + (size_t)bm * 256 * KDIM;
    const __hip_bfloat16* Bbase   = Wb  + (size_t)bn * 256 * KDIM;

    // --- A staging source (inverse of col^=(row&7) map; linear LDS dest) ---
    // dest chunk c: row r=c>>3, stored col sc=c&7 -> source col s=sc^(r&7).
    int gAoff[4], lOffA[4];
#pragma unroll
    for (int j = 0; j < 4; ++j) {
        const int c = wid * 256 + j * 64 + lane;
        const int r = c >> 3;
        const int s = (c & 7) ^ (r & 7);
        gAoff[j] = r * KDIM + s * 4;          // fp32 elements
        lOffA[j] = wid * 4096 + j * 1024;     // bytes (wave-uniform)
    }

    // --- B staging source (R2 map, verbatim) ---
    const int c0  = wid * 64 + lane;
    const int c1  = 512 + c0;
    const int cs0 = c0 ^ ((c0 >> 3) & 7);
    const int cs1 = c1 ^ ((c1 >> 3) & 7);
    const int gOffB0 = (cs0 >> 2) * KDIM + (cs0 & 3) * 8;   // bf16 elements
    const int gOffB1 = (cs1 >> 2) * KDIM + (cs1 & 3) * 8;
    const int lOffB0 = wid * 1024;
    const int lOffB1 = 8192 + wid * 1024;

    // --- fragment read offsets ---
    const int rsel = lane & 15;
    const int kq   = lane >> 4;             // 0..3
    int offA32[8][2];
#pragma unroll
    for (int m = 0; m < 8; ++m) {
        const int row = wr * 128 + m * 16 + rsel;
#pragma unroll
        for (int e = 0; e < 2; ++e) {
            const int col = (kq * 2 + e) ^ (row & 7);
            offA32[m][e] = row * 128 + col * 16;   // bytes in 32KB A slot
        }
    }
    int offB[4];
#pragma unroll
    for (int n = 0; n < 4; ++n) {
        int a = (wc * 64 + n * 16 + rsel) * 64 + kq * 16;
        offB[n] = a ^ (((a >> 7) & 7) << 4);       // bytes in 16KB B slot
    }

    f32x4 acc[8][4];
#pragma unroll
    for (int m = 0; m < 8; ++m)
#pragma unroll
        for (int n = 0; n < 4; ++n)
            acc[m][n] = (f32x4){0.f, 0.f, 0.f, 0.f};

    bf16x8 af0, af1, af2, af3, bf0, bf1, bf2, bf3;
    f32x4  u0, u1, u2, u3, u4, u5, u6, u7;

    // --- prologue: stage tile0 -> buf0, tile1 -> buf1 (12 gloads/wave) ---
    AST(0, 0, 0); AST(0, 0, 1); AST(0, 0, 2); AST(0, 0, 3); BST0(0, 0); BST1(0, 0);
    AST(1, 1, 0); AST(1, 1, 1); AST(1, 1, 2); AST(1, 1, 3); BST0(1, 1); BST1(1, 1);
    WAIT6;                    // tile0 landed; tile1's 6 may stay in flight
    __builtin_amdgcn_sched_barrier(0);
    __builtin_amdgcn_s_barrier();
    __builtin_amdgcn_sched_barrier(0);

    // --- main loop: KDIM/32 = 64 K-tiles, buf = t%3 ---
    for (int t = 0; t < 60; t += 3) {
        KT(t,     0, 2, 1, WAIT6);
        KT(t + 1, 1, 0, 1, WAIT6);
        KT(t + 2, 2, 1, 1, WAIT6);
    }
    KT(60, 0, 2, 1, WAIT6);   // stages t62
    KT(61, 1, 0, 1, WAIT6);   // stages t63
    KT(62, 2, 1, 0, WAIT0);   // drain: t63 landed
    KT(63, 0, 1, 0, WNONE);

    // --- epilogue: C/D layout col = lane&15, row = (lane>>4)*4 + r ---
    const int col0 = lane & 15;
    const int r0   = kq * 4;
#pragma unroll
    for (int n = 0; n < 4; ++n) {
        const int cg = bn * 256 + wc * 64 + n * 16 + col0;
        const float bv = bias[cg];
#pragma unroll
        for (int m = 0; m < 8; ++m) {
            const size_t rg = (size_t)bm * 256 + wr * 128 + m * 16 + r0;
#pragma unroll
            for (int r = 0; r < 4; ++r)
                C[(rg + r) * NDIM + cg] = acc[m][n][r] + bv;
        }
    }
}

// ---------------------------------------------------------------------------
// Fallback: naive fused fp32 GEMM (only if workspace too small).
// ---------------------------------------------------------------------------
__global__ void naive_kernel(const float* __restrict__ x,
                             const float* __restrict__ leaf,
                             const float* __restrict__ W,
                             const float* __restrict__ bias,
                             float* __restrict__ out) {
    long idx = (long)blockIdx.x * blockDim.x + threadIdx.x;
    if (idx >= (long)MROWS * NDIM) return;
    int  o = (int)(idx % NDIM);
    long m = idx / NDIM;
    int o2 = o / 169, o1 = (o / 13) % 13, o0 = o % 13;
    float acc = 0.f;
    for (int i = 0; i < KDIM; ++i) {
        int i2 = i / 169, i1 = (i / 13) % 13, i0 = i % 13;
        float d = 0.f;
#pragma unroll
        for (int r = 0; r < RANKD; ++r)
            d += leaf[( r     * LEAFD + o2) * LEAFD + i2]
               * leaf[((4 + r) * LEAFD + o1) * LEAFD + i1]
               * leaf[((8 + r) * LEAFD + o0) * LEAFD + i0];
        acc += x[m * KDIM + i] * (W[(long)o * KDIM + i] + d);
    }
    out[idx] = acc + bias[o];
}

// ---------------------------------------------------------------------------
extern "C" void kernel_launch(void* const* d_in, const int* in_sizes, int n_in,
                              void* d_out, int out_size, void* d_ws, size_t ws_size,
                              hipStream_t stream) {
    const float* x      = (const float*)d_in[0];
    const float* leaf   = (const float*)d_in[1];
    const float* weight = (const float*)d_in[2];
    const float* bias   = (const float*)d_in[3];
    float* out = (float*)d_out;

    const size_t needW = (size_t)NDIM * KDIM * sizeof(__hip_bfloat16);  // 8 MiB

    if (ws_size >= needW) {
        __hip_bfloat16* wb = (__hip_bfloat16*)d_ws;
        build_w_kernel<<<(NDIM * KDIM + 255) / 256, 256, 0, stream>>>(weight, leaf, wb);
        gemm6_kernel<<<(MROWS / 256) * (NDIM / 256), 512, 0, stream>>>(x, wb, bias, out);
    } else {
        long total = (long)MROWS * NDIM;
        naive_kernel<<<(int)((total + 255) / 256), 256, 0, stream>>>(x, leaf, weight, bias, out);
    }
}

// Round 11
// 202.730 us; speedup vs baseline: 1.1473x; 1.0479x over previous
//
#include <hip/hip_runtime.h>
#include <hip/hip_bf16.h>
#include <stdint.h>

#define MROWS 16384   // B*S
#define KDIM  2048
#define NDIM  2048
#define LEAFD 13
#define RANKD 4

typedef __bf16 bf16x8 __attribute__((ext_vector_type(8)));
typedef float  f32x4  __attribute__((ext_vector_type(4)));

// ---------------------------------------------------------------------------
// Kernel 1: w_bf[o,i] = bf16( weight[o,i] + sum_r L0[r,o2,i2]*L1[r,o1,i1]*L2[r,o0,i0] )
// ---------------------------------------------------------------------------
__global__ void build_w_kernel(const float* __restrict__ weight,
                               const float* __restrict__ leaf,
                               __hip_bfloat16* __restrict__ wbf) {
    __shared__ float ll[3 * RANKD * LEAFD * LEAFD];
    for (int t = threadIdx.x; t < 3 * RANKD * LEAFD * LEAFD; t += blockDim.x)
        ll[t] = leaf[t];
    __syncthreads();
    int idx = blockIdx.x * blockDim.x + threadIdx.x;
    if (idx >= NDIM * KDIM) return;
    int o = idx / KDIM, i = idx % KDIM;
    int o2 = o / 169, o1 = (o / 13) % 13, o0 = o % 13;
    int i2 = i / 169, i1 = (i / 13) % 13, i0 = i % 13;
    float d = 0.f;
#pragma unroll
    for (int r = 0; r < RANKD; ++r) {
        float a = ll[( r            * LEAFD + o2) * LEAFD + i2];
        float b = ll[((RANKD   + r) * LEAFD + o1) * LEAFD + i1];
        float c = ll[((2*RANKD + r) * LEAFD + o0) * LEAFD + i0];
        d += a * b * c;
    }
    wbf[idx] = __float2bfloat16(weight[idx] + d);
}

// ---------------------------------------------------------------------------
// Kernel 2: fp32 -> bf16 conversion of activations (8 floats/thread)
// ---------------------------------------------------------------------------
__global__ void cvt_kernel(const float* __restrict__ x,
                           __hip_bfloat16* __restrict__ xb, int n) {
    long stride = (long)gridDim.x * blockDim.x * 8;
    for (long idx = ((long)blockIdx.x * blockDim.x + threadIdx.x) * 8; idx < n; idx += stride) {
        float4 v0 = *reinterpret_cast<const float4*>(x + idx);
        float4 v1 = *reinterpret_cast<const float4*>(x + idx + 4);
        __hip_bfloat16 tmp[8];
        tmp[0] = __float2bfloat16(v0.x); tmp[1] = __float2bfloat16(v0.y);
        tmp[2] = __float2bfloat16(v0.z); tmp[3] = __float2bfloat16(v0.w);
        tmp[4] = __float2bfloat16(v1.x); tmp[5] = __float2bfloat16(v1.y);
        tmp[6] = __float2bfloat16(v1.z); tmp[7] = __float2bfloat16(v1.w);
        *reinterpret_cast<uint4*>(xb + idx) = *reinterpret_cast<const uint4*>(tmp);
    }
}

// ---------------------------------------------------------------------------
// Kernel 3: 256x256 tile, BK=32, 16x16x32 MFMA, ONE barrier per K-tile,
// NO internal sched_barrier pins — overlap via wave skew + compiler-counted
// waits. 512 threads = 8 waves (2M x 4N); per-wave output 128x64.
//
// LDS: 4 bufs x {A 16KB, B 16KB} = 128 KB. Stage tile t+3 during tile t via
// global_load_lds (4 gloads/wave). Counted vmcnt at tile end: steady-state
// outstanding {t+1,t+2,t+3} x4 -> vmcnt(8) guarantees t+1 landed (issued 2
// full tiles = ~2500 cyc earlier; HBM latency fully hidden). The vmcnt asm's
// "memory" clobber is also the compiler fence preventing next-tile LDS reads
// from hoisting above the barrier.
//
// All LDS maps are R2's measured-zero-conflict maps verbatim: storage
// involution swz(p)=p^((p>>3)&7) on 16B chunks of a 16KB slot; each wave
// ds_read_b128 bijects onto one contiguous 1KB block (16 rows x 4 k-chunks).
// ---------------------------------------------------------------------------

__device__ __forceinline__ void gload16(const __hip_bfloat16* g, char* l) {
    __builtin_amdgcn_global_load_lds((const __attribute__((address_space(1))) void*)g,
                                     (__attribute__((address_space(3))) void*)l,
                                     16, 0, 0);
}

// Stage one 16KB slot (A or B) of k-tile kt into buf BS.
#define ASTG(kt, BS) do {                                                       \
    gload16(Abase + (kt)*32 + gOff0, smemc + (BS)*32768 + lOff0);               \
    gload16(Abase + (kt)*32 + gOff1, smemc + (BS)*32768 + lOff1);               \
} while (0)
#define BSTG(kt, BS) do {                                                       \
    gload16(Bbase + (kt)*32 + gOff0, smemc + (BS)*32768 + 16384 + lOff0);       \
    gload16(Bbase + (kt)*32 + gOff1, smemc + (BS)*32768 + 16384 + lOff1);       \
} while (0)

#define LOAD_B(BC)                                                              \
    bf0 = *(const bf16x8*)(smemc + (BC)*32768 + 16384 + offB[0]);               \
    bf1 = *(const bf16x8*)(smemc + (BC)*32768 + 16384 + offB[1]);               \
    bf2 = *(const bf16x8*)(smemc + (BC)*32768 + 16384 + offB[2]);               \
    bf3 = *(const bf16x8*)(smemc + (BC)*32768 + 16384 + offB[3]);

#define LOAD_A0(BC)                                                             \
    af0 = *(const bf16x8*)(smemc + (BC)*32768 + offA[0]);                       \
    af1 = *(const bf16x8*)(smemc + (BC)*32768 + offA[1]);                       \
    af2 = *(const bf16x8*)(smemc + (BC)*32768 + offA[2]);                       \
    af3 = *(const bf16x8*)(smemc + (BC)*32768 + offA[3]);

#define LOAD_A1(BC)                                                             \
    ag0 = *(const bf16x8*)(smemc + (BC)*32768 + offA[4]);                       \
    ag1 = *(const bf16x8*)(smemc + (BC)*32768 + offA[5]);                       \
    ag2 = *(const bf16x8*)(smemc + (BC)*32768 + offA[6]);                       \
    ag3 = *(const bf16x8*)(smemc + (BC)*32768 + offA[7]);

#define MFMA_MH0 do {                                                                     \
    acc[0][0] = __builtin_amdgcn_mfma_f32_16x16x32_bf16(af0, bf0, acc[0][0], 0,0,0);      \
    acc[1][0] = __builtin_amdgcn_mfma_f32_16x16x32_bf16(af1, bf0, acc[1][0], 0,0,0);      \
    acc[2][0] = __builtin_amdgcn_mfma_f32_16x16x32_bf16(af2, bf0, acc[2][0], 0,0,0);      \
    acc[3][0] = __builtin_amdgcn_mfma_f32_16x16x32_bf16(af3, bf0, acc[3][0], 0,0,0);      \
    acc[0][1] = __builtin_amdgcn_mfma_f32_16x16x32_bf16(af0, bf1, acc[0][1], 0,0,0);      \
    acc[1][1] = __builtin_amdgcn_mfma_f32_16x16x32_bf16(af1, bf1, acc[1][1], 0,0,0);      \
    acc[2][1] = __builtin_amdgcn_mfma_f32_16x16x32_bf16(af2, bf1, acc[2][1], 0,0,0);      \
    acc[3][1] = __builtin_amdgcn_mfma_f32_16x16x32_bf16(af3, bf1, acc[3][1], 0,0,0);      \
    acc[0][2] = __builtin_amdgcn_mfma_f32_16x16x32_bf16(af0, bf2, acc[0][2], 0,0,0);      \
    acc[1][2] = __builtin_amdgcn_mfma_f32_16x16x32_bf16(af1, bf2, acc[1][2], 0,0,0);      \
    acc[2][2] = __builtin_amdgcn_mfma_f32_16x16x32_bf16(af2, bf2, acc[2][2], 0,0,0);      \
    acc[3][2] = __builtin_amdgcn_mfma_f32_16x16x32_bf16(af3, bf2, acc[3][2], 0,0,0);      \
    acc[0][3] = __builtin_amdgcn_mfma_f32_16x16x32_bf16(af0, bf3, acc[0][3], 0,0,0);      \
    acc[1][3] = __builtin_amdgcn_mfma_f32_16x16x32_bf16(af1, bf3, acc[1][3], 0,0,0);      \
    acc[2][3] = __builtin_amdgcn_mfma_f32_16x16x32_bf16(af2, bf3, acc[2][3], 0,0,0);      \
    acc[3][3] = __builtin_amdgcn_mfma_f32_16x16x32_bf16(af3, bf3, acc[3][3], 0,0,0);      \
} while (0)

#define MFMA_MH1 do {                                                                     \
    acc[4][0] = __builtin_amdgcn_mfma_f32_16x16x32_bf16(ag0, bf0, acc[4][0], 0,0,0);      \
    acc[5][0] = __builtin_amdgcn_mfma_f32_16x16x32_bf16(ag1, bf0, acc[5][0], 0,0,0);      \
    acc[6][0] = __builtin_amdgcn_mfma_f32_16x16x32_bf16(ag2, bf0, acc[6][0], 0,0,0);      \
    acc[7][0] = __builtin_amdgcn_mfma_f32_16x16x32_bf16(ag3, bf0, acc[7][0], 0,0,0);      \
    acc[4][1] = __builtin_amdgcn_mfma_f32_16x16x32_bf16(ag0, bf1, acc[4][1], 0,0,0);      \
    acc[5][1] = __builtin_amdgcn_mfma_f32_16x16x32_bf16(ag1, bf1, acc[5][1], 0,0,0);      \
    acc[6][1] = __builtin_amdgcn_mfma_f32_16x16x32_bf16(ag2, bf1, acc[6][1], 0,0,0);      \
    acc[7][1] = __builtin_amdgcn_mfma_f32_16x16x32_bf16(ag3, bf1, acc[7][1], 0,0,0);      \
    acc[4][2] = __builtin_amdgcn_mfma_f32_16x16x32_bf16(ag0, bf2, acc[4][2], 0,0,0);      \
    acc[5][2] = __builtin_amdgcn_mfma_f32_16x16x32_bf16(ag1, bf2, acc[5][2], 0,0,0);      \
    acc[6][2] = __builtin_amdgcn_mfma_f32_16x16x32_bf16(ag2, bf2, acc[6][2], 0,0,0);      \
    acc[7][2] = __builtin_amdgcn_mfma_f32_16x16x32_bf16(ag3, bf2, acc[7][2], 0,0,0);      \
    acc[4][3] = __builtin_amdgcn_mfma_f32_16x16x32_bf16(ag0, bf3, acc[4][3], 0,0,0);      \
    acc[5][3] = __builtin_amdgcn_mfma_f32_16x16x32_bf16(ag1, bf3, acc[5][3], 0,0,0);      \
    acc[6][3] = __builtin_amdgcn_mfma_f32_16x16x32_bf16(ag2, bf3, acc[6][3], 0,0,0);      \
    acc[7][3] = __builtin_amdgcn_mfma_f32_16x16x32_bf16(ag3, bf3, acc[7][3], 0,0,0);      \
} while (0)

#define WAIT8 asm volatile("s_waitcnt vmcnt(8)" ::: "memory")
#define WAIT4 asm volatile("s_waitcnt vmcnt(4)" ::: "memory")
#define WAIT0 asm volatile("s_waitcnt vmcnt(0)" ::: "memory")

// One K-tile, one barrier, no pins. Compiler emits counted lgkm waits for the
// ds_read->MFMA deps; wave skew inside the span overlaps LDS reads with MFMA.
#define KT(t, BC, BS, SG, WT) do {                                  \
    LOAD_B(BC); LOAD_A0(BC); LOAD_A1(BC);                           \
    if (SG) { ASTG((t)+3, BS); BSTG((t)+3, BS); }                   \
    __builtin_amdgcn_s_setprio(1);                                  \
    MFMA_MH0; MFMA_MH1;                                             \
    __builtin_amdgcn_s_setprio(0);                                  \
    WT;                                                             \
    __builtin_amdgcn_s_barrier();                                   \
} while (0)

#define KT_LAST(BC) do {                                            \
    LOAD_B(BC); LOAD_A0(BC); LOAD_A1(BC);                           \
    __builtin_amdgcn_s_setprio(1);                                  \
    MFMA_MH0; MFMA_MH1;                                             \
    __builtin_amdgcn_s_setprio(0);                                  \
} while (0)

__global__ __launch_bounds__(512, 1) void gemm7_kernel(const __hip_bfloat16* __restrict__ A,
                                                       const __hip_bfloat16* __restrict__ Wb,
                                                       const float* __restrict__ bias,
                                                       float* __restrict__ C) {
    __shared__ __align__(16) char smem_raw[4 * 32768];   // 128 KiB
    char* smemc = smem_raw;

    const int tid  = threadIdx.x;
    const int lane = tid & 63;
    const int wid  = tid >> 6;        // 0..7
    const int wr   = wid >> 2;        // 0..1  (M half)
    const int wc   = wid & 3;         // 0..3  (N quarter)

    // T1: XCD-aware swizzle (nwg=512, 512%8==0 -> bijective).
    const int bid = blockIdx.x;
    const int swz = (bid & 7) * 64 + (bid >> 3);
    const int bn  = swz >> 6;         // 0..7
    const int bm  = swz & 63;         // 0..63

    const __hip_bfloat16* Abase = A  + (size_t)bm * 256 * KDIM;
    const __hip_bfloat16* Bbase = Wb + (size_t)bn * 256 * KDIM;

    // --- staging source offsets (inverse-swizzled global, linear LDS dest) ---
    const int c0  = wid * 64 + lane;          // chunk 0..511
    const int c1  = 512 + c0;                 // chunk 512..1023
    const int cs0 = c0 ^ ((c0 >> 3) & 7);
    const int cs1 = c1 ^ ((c1 >> 3) & 7);
    const int gOff0 = (cs0 >> 2) * KDIM + (cs0 & 3) * 8;   // bf16 elements
    const int gOff1 = (cs1 >> 2) * KDIM + (cs1 & 3) * 8;
    const int lOff0 = wid * 1024;                          // bytes (wave-uniform)
    const int lOff1 = 8192 + wid * 1024;

    // --- swizzled ds_read byte offsets within a 16 KB slot (R2 map, 0-conflict) ---
    const int rsel = lane & 15;
    const int kby  = (lane >> 4) * 16;
    int offA[8], offB[4];
#pragma unroll
    for (int m = 0; m < 8; ++m) {
        int a = (wr * 128 + m * 16 + rsel) * 64 + kby;
        offA[m] = a ^ (((a >> 7) & 7) << 4);
    }
#pragma unroll
    for (int n = 0; n < 4; ++n) {
        int a = (wc * 64 + n * 16 + rsel) * 64 + kby;
        offB[n] = a ^ (((a >> 7) & 7) << 4);
    }

    f32x4 acc[8][4];
#pragma unroll
    for (int m = 0; m < 8; ++m)
#pragma unroll
        for (int n = 0; n < 4; ++n)
            acc[m][n] = (f32x4){0.f, 0.f, 0.f, 0.f};

    bf16x8 af0, af1, af2, af3, ag0, ag1, ag2, ag3, bf0, bf1, bf2, bf3;

    // --- prologue: stage tiles 0,1,2 -> bufs 0,1,2 (12 gloads/wave) ---
    ASTG(0, 0); BSTG(0, 0);
    ASTG(1, 1); BSTG(1, 1);
    ASTG(2, 2); BSTG(2, 2);
    WAIT8;                    // tile0 landed; tiles 1,2 may stay in flight
    __builtin_amdgcn_s_barrier();

    // --- main loop: KDIM/32 = 64 K-tiles, buf = t&3, stage t+3 ---
    for (int t = 0; t < 60; t += 4) {
        KT(t,     0, 3, 1, WAIT8);
        KT(t + 1, 1, 0, 1, WAIT8);
        KT(t + 2, 2, 1, 1, WAIT8);
        KT(t + 3, 3, 2, 1, WAIT8);
    }
    KT(60, 0, 3, 1, WAIT8);   // stages tile 63 -> buf3
    KT(61, 1, 0, 0, WAIT4);   // outstanding {62,63} -> 62 landed
    KT(62, 2, 0, 0, WAIT0);   // 63 landed
    KT_LAST(3);               // tile 63

    // --- epilogue: C/D layout col = lane&15, row = (lane>>4)*4 + r ---
    const int col0 = lane & 15;
    const int r0   = (lane >> 4) * 4;
#pragma unroll
    for (int n = 0; n < 4; ++n) {
        const int cg = bn * 256 + wc * 64 + n * 16 + col0;
        const float bv = bias[cg];
#pragma unroll
        for (int m = 0; m < 8; ++m) {
            const size_t rg = (size_t)bm * 256 + wr * 128 + m * 16 + r0;
#pragma unroll
            for (int r = 0; r < 4; ++r)
                C[(rg + r) * NDIM + cg] = acc[m][n][r] + bv;
        }
    }
}

// ---------------------------------------------------------------------------
// Fallback: naive fused fp32 GEMM (only if workspace too small).
// ---------------------------------------------------------------------------
__global__ void naive_kernel(const float* __restrict__ x,
                             const float* __restrict__ leaf,
                             const float* __restrict__ W,
                             const float* __restrict__ bias,
                             float* __restrict__ out) {
    long idx = (long)blockIdx.x * blockDim.x + threadIdx.x;
    if (idx >= (long)MROWS * NDIM) return;
    int  o = (int)(idx % NDIM);
    long m = idx / NDIM;
    int o2 = o / 169, o1 = (o / 13) % 13, o0 = o % 13;
    float acc = 0.f;
    for (int i = 0; i < KDIM; ++i) {
        int i2 = i / 169, i1 = (i / 13) % 13, i0 = i % 13;
        float d = 0.f;
#pragma unroll
        for (int r = 0; r < RANKD; ++r)
            d += leaf[( r     * LEAFD + o2) * LEAFD + i2]
               * leaf[((4 + r) * LEAFD + o1) * LEAFD + i1]
               * leaf[((8 + r) * LEAFD + o0) * LEAFD + i0];
        acc += x[m * KDIM + i] * (W[(long)o * KDIM + i] + d);
    }
    out[idx] = acc + bias[o];
}

// ---------------------------------------------------------------------------
extern "C" void kernel_launch(void* const* d_in, const int* in_sizes, int n_in,
                              void* d_out, int out_size, void* d_ws, size_t ws_size,
                              hipStream_t stream) {
    const float* x      = (const float*)d_in[0];
    const float* leaf   = (const float*)d_in[1];
    const float* weight = (const float*)d_in[2];
    const float* bias   = (const float*)d_in[3];
    float* out = (float*)d_out;

    const size_t needA = (size_t)MROWS * KDIM * sizeof(__hip_bfloat16);  // 64 MiB
    const size_t needW = (size_t)NDIM  * KDIM * sizeof(__hip_bfloat16);  // 8 MiB

    if (ws_size >= needA + needW) {
        __hip_bfloat16* xb = (__hip_bfloat16*)d_ws;
        __hip_bfloat16* wb = (__hip_bfloat16*)((char*)d_ws + needA);
        build_w_kernel<<<(NDIM * KDIM + 255) / 256, 256, 0, stream>>>(weight, leaf, wb);
        cvt_kernel<<<2048, 256, 0, stream>>>(x, xb, MROWS * KDIM);
        gemm7_kernel<<<(MROWS / 256) * (NDIM / 256), 512, 0, stream>>>(xb, wb, bias, out);
    } else {
        long total = (long)MROWS * NDIM;
        naive_kernel<<<(int)((total + 255) / 256), 256, 0, stream>>>(x, leaf, weight, bias, out);
    }
}